// Round 1
// baseline (958.172 us; speedup 1.0000x reference)
//
#include <hip/hip_runtime.h>

// Phi3 quantized MLP on MI355X (gfx950) — R6: double-buffered counted-vmcnt pipeline (T3+T4+T5).
// R5 post-mortem: MfmaUtil 30%, VALUBusy 47%, HBM 8% -> stall-bound. The K-loop was
// single-buffered: __syncthreads() right after issuing global_load_lds drains vmcnt(0) on
// just-issued loads -> full load latency exposed every K-step (the documented m97-structure
// stall). Fix: dbuf LDS, one raw s_barrier + vmcnt(0)-on-PREVIOUS-iter's-loads per K-step,
// stage issued right after the barrier so its latency hides under this iter's MFMA+rescale,
// s_setprio(1) around the MFMA cluster. gemm_gateup moves to 512 thr (3 operands dbuf =
// 96 KB LDS -> 1 block/CU, 8 waves). gemm_down keeps 256 thr (64 KB dbuf -> 2 blocks/CU).
// Scale loads are issued BEFORE stage loads each iter: vmcnt is FIFO, so the compiler's
// auto-wait before the rescale becomes vmcnt(6/8) instead of a drain.

typedef float f32x4 __attribute__((ext_vector_type(4)));
typedef float f32x2 __attribute__((ext_vector_type(2)));
typedef int   i32x4 __attribute__((ext_vector_type(4)));

__device__ __forceinline__ void gload16(const void* g, void* l) {
  __builtin_amdgcn_global_load_lds(
      (const __attribute__((address_space(1))) void*)g,
      (__attribute__((address_space(3))) void*)l, 16, 0, 0);
}

// ---------------- quantize x: f32 -> int8, scale per (row-quad of 4, group of 128) ----------------
// grid (24, 1024): g = blockIdx.x, row-quad = blockIdx.y. Xs4: [24][1024]
__global__ __launch_bounds__(256) void quant_x(const float* __restrict__ x,
                                               signed char* __restrict__ Xq,
                                               float* __restrict__ Xs4) {
  int g    = blockIdx.x;
  int rq   = blockIdx.y;
  int w    = threadIdx.x >> 6;
  int lane = threadIdx.x & 63;
  int row  = rq * 4 + w;
  __shared__ float wmax[4];
  const float2 v = *(const float2*)(x + (size_t)row * 3072 + g * 128 + lane * 2);
  float m = fmaxf(fabsf(v.x), fabsf(v.y));
#pragma unroll
  for (int s = 1; s < 64; s <<= 1) m = fmaxf(m, __shfl_xor(m, s));
  if (lane == 0) wmax[w] = m;
  __syncthreads();
  float m4 = fmaxf(fmaxf(wmax[0], wmax[1]), fmaxf(wmax[2], wmax[3]));
  float inv = m4 > 0.f ? 127.f / m4 : 0.f;
  int qa = (int)rintf(v.x * inv);
  int qb = (int)rintf(v.y * inv);
  unsigned short pk = (unsigned short)((qa & 0xff) | ((qb & 0xff) << 8));
  *(unsigned short*)(Xq + (size_t)row * 3072 + g * 128 + lane * 2) = pk;
  if (threadIdx.x == 0) Xs4[g * 1024 + rq] = m4 * (1.f / 127.f);
}

// ---------------- requant weights: int32 q,z -> int8 (q - z), exact ----------------
template <int K>
__global__ __launch_bounds__(256) void requant_k(const int* __restrict__ qw,
                                                 const int* __restrict__ qz,
                                                 signed char* __restrict__ W) {
  constexpr int KG = K / 128;
  constexpr int perrow = K / 8;
  int idx = blockIdx.x * 256 + threadIdx.x;
  int row = idx / perrow;
  int c8  = idx - row * perrow;
  int k   = c8 << 3;
  int z   = qz[row * KG + (k >> 7)];
  const int4* q4 = (const int4*)(qw + (size_t)row * K + k);
  int4 qa = q4[0];
  int4 qb = q4[1];
  int b0 = ((qa.x - z) & 0xff) | (((qa.y - z) & 0xff) << 8) |
           (((qa.z - z) & 0xff) << 16) | (((qa.w - z) & 0xff) << 24);
  int b1 = ((qb.x - z) & 0xff) | (((qb.y - z) & 0xff) << 8) |
           (((qb.z - z) & 0xff) << 16) | (((qb.w - z) & 0xff) << 24);
  int2 o; o.x = b0; o.y = b1;
  *(int2*)(W + (size_t)row * K + k) = o;
}

// ---------------- scale transpose: [R][G] -> [G][R] ----------------
__global__ __launch_bounds__(256) void transpose_sc(const float* __restrict__ in,
                                                    float* __restrict__ out,
                                                    int R, int G) {
  int idx = blockIdx.x * 256 + threadIdx.x;
  int r = idx / G;
  int g = idx - r * G;
  out[(size_t)g * R + r] = in[idx];
}

// LDS tile: 128 rows x 128 bytes, XOR-swizzled (phys chunk p holds logical p^(row&7)).

// ---------------- GEMM1: act = silu(x@Wg^T)*(x@Wu^T), int8 in, int8 out ----------------
// 512 threads, 8 waves in a 2(M)x4(N) grid; per-wave 64x32 of both gate and up.
// Double-buffered A/G/U tiles (2 x 48 KB), rotation pipeline.
__global__ __launch_bounds__(512, 2) void gemm_gateup_i8(
    const signed char* __restrict__ Xq, const signed char* __restrict__ Wq,
    const float* __restrict__ Xs4,   // [24][1024]
    const float* __restrict__ GsT,   // [24][16384]
    signed char* __restrict__ act,   // [4096][8192]
    float* __restrict__ As4) {       // [64][1024]
  const int K = 3072;
  const int bid = blockIdx.x;
  const int xcd = bid & 7;
  const int jb  = bid >> 3;
  const int n0  = ((xcd << 3) + (jb & 7)) * 128;
  const int m0  = (jb >> 3) * 128;
  __shared__ __align__(16) signed char smem[98304];   // [2][A 16K | G 16K | U 16K]
  __shared__ float rmax[4][128];
  __shared__ float rmax4[32];

  const int tid  = threadIdx.x;
  const int l    = tid & 63;
  const int quad = l >> 4;
  const int l16  = l & 15;
  const int w    = tid >> 6;
  const int wr   = (w >> 2) * 64;   // 0 or 64
  const int wc   = (w & 3) * 32;    // 0,32,64,96

  f32x2 fg[4][2][2] = {};
  f32x2 fu[4][2][2] = {};

  int off[2];
#pragma unroll
  for (int t = 0; t < 2; ++t) {
    int c   = tid + 512 * t;
    int row = c >> 3;
    int log = (c & 7) ^ (row & 7);
    off[t] = row * K + log * 16;
  }
  const signed char* baseA = Xq + (size_t)m0 * K;
  const signed char* baseG = Wq + (size_t)n0 * K;
  const signed char* baseU = Wq + (size_t)(8192 + n0) * K;

  int aoff[2][4], boff[2][2];
#pragma unroll
  for (int h = 0; h < 2; ++h) {
    int slot = h * 4 + quad;
#pragma unroll
    for (int i = 0; i < 4; ++i) {
      int ra = wr + i * 16 + l16;
      aoff[h][i] = ra * 128 + ((slot ^ (ra & 7)) * 16);
    }
#pragma unroll
    for (int jj = 0; jj < 2; ++jj) {
      int rb = wc + jj * 16 + l16;
      boff[h][jj] = rb * 128 + ((slot ^ (rb & 7)) * 16);
    }
  }
  const int qbase = (m0 >> 2) + (wr >> 2) + quad;

  // prologue: stage tile 0 into half 0
#pragma unroll
  for (int t = 0; t < 2; ++t) {
    gload16(baseA + off[t], smem + (tid + 512 * t) * 16);
    gload16(baseG + off[t], smem + 16384 + (tid + 512 * t) * 16);
    gload16(baseU + off[t], smem + 32768 + (tid + 512 * t) * 16);
  }

  int cur = 0;
  for (int g = 0; g < 24; ++g) {
    // tile g's staging was issued one full compute phase ago -> latency already hidden.
    asm volatile("s_waitcnt vmcnt(0)" ::: "memory");
    __builtin_amdgcn_s_barrier();
    __builtin_amdgcn_sched_barrier(0);

    // scales FIRST (so compiler's wait before rescale leaves the stage loads in flight)
    float sxq[4], sg[2], su[2];
#pragma unroll
    for (int i = 0; i < 4; ++i) sxq[i] = Xs4[g * 1024 + qbase + i * 4];
#pragma unroll
    for (int jj = 0; jj < 2; ++jj) {
      sg[jj] = GsT[g * 16384 + n0 + wc + jj * 16 + l16];
      su[jj] = GsT[g * 16384 + 8192 + n0 + wc + jj * 16 + l16];
    }
    __builtin_amdgcn_sched_barrier(0);

    if (g < 23) {   // stage tile g+1 into the other half; flies under this iter's MFMAs
      const int s1 = (cur ^ 1) * 49152;
      const int kk = (g + 1) << 7;
#pragma unroll
      for (int t = 0; t < 2; ++t) {
        gload16(baseA + off[t] + kk, smem + s1 + (tid + 512 * t) * 16);
        gload16(baseG + off[t] + kk, smem + s1 + 16384 + (tid + 512 * t) * 16);
        gload16(baseU + off[t] + kk, smem + s1 + 32768 + (tid + 512 * t) * 16);
      }
    }

    const signed char* A0 = smem + cur * 49152;
    const signed char* G0 = A0 + 16384;
    const signed char* U0 = A0 + 32768;

    i32x4 a[4][2];
#pragma unroll
    for (int i = 0; i < 4; ++i) {
      a[i][0] = *(const i32x4*)(A0 + aoff[0][i]);
      a[i][1] = *(const i32x4*)(A0 + aoff[1][i]);
    }
    __builtin_amdgcn_s_setprio(1);
#pragma unroll
    for (int jj = 0; jj < 2; ++jj) {
      i32x4 bg0 = *(const i32x4*)(G0 + boff[0][jj]);
      i32x4 bg1 = *(const i32x4*)(G0 + boff[1][jj]);
      i32x4 bu0 = *(const i32x4*)(U0 + boff[0][jj]);
      i32x4 bu1 = *(const i32x4*)(U0 + boff[1][jj]);
#pragma unroll
      for (int i = 0; i < 4; ++i) {
        i32x4 zero = {0, 0, 0, 0};
        i32x4 ig = __builtin_amdgcn_mfma_i32_16x16x64_i8(a[i][0], bg0, zero, 0, 0, 0);
        ig = __builtin_amdgcn_mfma_i32_16x16x64_i8(a[i][1], bg1, ig, 0, 0, 0);
        i32x4 iu = __builtin_amdgcn_mfma_i32_16x16x64_i8(a[i][0], bu0, zero, 0, 0, 0);
        iu = __builtin_amdgcn_mfma_i32_16x16x64_i8(a[i][1], bu1, iu, 0, 0, 0);
        float pgs = sxq[i] * sg[jj];
        float pus = sxq[i] * su[jj];
        f32x2 pg2 = {pgs, pgs};
        f32x2 pu2 = {pus, pus};
        f32x2 g01 = {(float)ig[0], (float)ig[1]};
        f32x2 g23 = {(float)ig[2], (float)ig[3]};
        f32x2 u01 = {(float)iu[0], (float)iu[1]};
        f32x2 u23 = {(float)iu[2], (float)iu[3]};
        fg[i][jj][0] = __builtin_elementwise_fma(g01, pg2, fg[i][jj][0]);
        fg[i][jj][1] = __builtin_elementwise_fma(g23, pg2, fg[i][jj][1]);
        fu[i][jj][0] = __builtin_elementwise_fma(u01, pu2, fu[i][jj][0]);
        fu[i][jj][1] = __builtin_elementwise_fma(u23, pu2, fu[i][jj][1]);
      }
    }
    __builtin_amdgcn_s_setprio(0);
    cur ^= 1;
  }

  // ---- epilogue: silu(g)*u -> quad-shared absmax -> int8 ----
  float av[4][2][4];   // [i][jj][r]
#pragma unroll
  for (int i = 0; i < 4; ++i)
#pragma unroll
    for (int jj = 0; jj < 2; ++jj)
#pragma unroll
      for (int r = 0; r < 4; ++r) {
        float gv = fg[i][jj][r >> 1][r & 1];
        float uv = fu[i][jj][r >> 1][r & 1];
        av[i][jj][r] = (gv / (1.f + __expf(-gv))) * uv;
      }

#pragma unroll
  for (int i = 0; i < 4; ++i)
#pragma unroll
    for (int r = 0; r < 4; ++r) {
      float m = fmaxf(fabsf(av[i][0][r]), fabsf(av[i][1][r]));
      m = fmaxf(m, __shfl_xor(m, 1));
      m = fmaxf(m, __shfl_xor(m, 2));
      m = fmaxf(m, __shfl_xor(m, 4));
      m = fmaxf(m, __shfl_xor(m, 8));
      if (l16 == 0) rmax[w & 3][wr + i * 16 + quad * 4 + r] = m;
    }
  __syncthreads();
  if (tid < 32) {
    float m = 0.f;
#pragma unroll
    for (int c = 0; c < 4; ++c)
#pragma unroll
      for (int k = 0; k < 4; ++k) m = fmaxf(m, rmax[c][tid * 4 + k]);
    rmax4[tid] = m;
    As4[(n0 >> 7) * 1024 + (m0 >> 2) + tid] = m * (1.f / 127.f);
  }
  __syncthreads();

#pragma unroll
  for (int i = 0; i < 4; ++i) {
    float mx = rmax4[(wr >> 2) + i * 4 + quad];
    float inv = mx > 0.f ? 127.f / mx : 0.f;
#pragma unroll
    for (int r = 0; r < 4; ++r) {
      int mrow = wr + i * 16 + quad * 4 + r;
#pragma unroll
      for (int jj = 0; jj < 2; ++jj) {
        int q = (int)rintf(av[i][jj][r] * inv);
        smem[mrow * 128 + wc + jj * 16 + l16] = (signed char)q;
      }
    }
  }
  __syncthreads();

#pragma unroll
  for (int t = 0; t < 2; ++t) {
    int c = tid + 512 * t;
    int row = c >> 3;
    int col = (c & 7) * 16;
    *(int4*)(act + (size_t)(m0 + row) * 8192 + n0 + col) = *(const int4*)(smem + row * 128 + col);
  }
}

// ---------------- GEMM2: out = dequant(act)@Wd^T + bias ----------------
// 256 threads, double-buffered A/B tiles (2 x 32 KB = 64 KB -> 2 blocks/CU), rotation pipeline.
__global__ __launch_bounds__(256, 2) void gemm_down_i8(
    const signed char* __restrict__ Aq, const signed char* __restrict__ Wq,
    const float* __restrict__ As4,   // [64][1024]
    const float* __restrict__ DsT,   // [64][3072]
    const float* __restrict__ bias,
    float* __restrict__ out) {
  const int K = 8192;
  const int bid = blockIdx.x;
  const int xcd = bid & 7;
  const int jb  = bid >> 3;
  const int jn  = jb % 12;
  const int jm  = jb / 12;
  const int n0  = (12 * (xcd & 1) + jn) * 128;
  const int m0  = (8 * (xcd >> 1) + jm) * 128;
  __shared__ __align__(16) signed char smem[65536];   // [2][A 16K | B 16K]

  const int tid  = threadIdx.x;
  const int l    = tid & 63;
  const int quad = l >> 4;
  const int l16  = l & 15;
  const int wr   = ((tid >> 6) >> 1) * 64;
  const int wc   = ((tid >> 6) & 1) * 64;

  f32x2 fc[4][4][2] = {};

  int off[4];
#pragma unroll
  for (int jj = 0; jj < 4; ++jj) {
    int c   = tid + 256 * jj;
    int row = c >> 3;
    int log = (c & 7) ^ (row & 7);
    off[jj] = row * K + log * 16;
  }
  const signed char* baseA = Aq + (size_t)m0 * K;
  const signed char* baseB = Wq + (size_t)n0 * K;

  int aoff[2][4], boff[2][4];
#pragma unroll
  for (int h = 0; h < 2; ++h) {
    int slot = h * 4 + quad;
#pragma unroll
    for (int i = 0; i < 4; ++i) {
      int ra = wr + i * 16 + l16;
      aoff[h][i] = ra * 128 + ((slot ^ (ra & 7)) * 16);
      int rb = wc + i * 16 + l16;
      boff[h][i] = rb * 128 + ((slot ^ (rb & 7)) * 16);
    }
  }
  const int qbase = (m0 >> 2) + (wr >> 2) + quad;

  // prologue: stage tile 0 into half 0
#pragma unroll
  for (int jj = 0; jj < 4; ++jj) {
    gload16(baseA + off[jj], smem + (tid + 256 * jj) * 16);
    gload16(baseB + off[jj], smem + 16384 + (tid + 256 * jj) * 16);
  }

  int cur = 0;
  for (int g = 0; g < 64; ++g) {
    asm volatile("s_waitcnt vmcnt(0)" ::: "memory");
    __builtin_amdgcn_s_barrier();
    __builtin_amdgcn_sched_barrier(0);

    float sxq[4], sn[4];
#pragma unroll
    for (int i = 0; i < 4; ++i) sxq[i] = As4[g * 1024 + qbase + i * 4];
#pragma unroll
    for (int jj = 0; jj < 4; ++jj)
      sn[jj] = DsT[g * 3072 + n0 + wc + jj * 16 + l16];
    __builtin_amdgcn_sched_barrier(0);

    if (g < 63) {
      const int s1 = (cur ^ 1) * 32768;
      const int kk = (g + 1) << 7;
#pragma unroll
      for (int jj = 0; jj < 4; ++jj) {
        gload16(baseA + off[jj] + kk, smem + s1 + (tid + 256 * jj) * 16);
        gload16(baseB + off[jj] + kk, smem + s1 + 16384 + (tid + 256 * jj) * 16);
      }
    }

    const signed char* A0 = smem + cur * 32768;
    const signed char* B0 = A0 + 16384;

    i32x4 a[4][2];
#pragma unroll
    for (int i = 0; i < 4; ++i) {
      a[i][0] = *(const i32x4*)(A0 + aoff[0][i]);
      a[i][1] = *(const i32x4*)(A0 + aoff[1][i]);
    }
    __builtin_amdgcn_s_setprio(1);
#pragma unroll
    for (int jj = 0; jj < 4; ++jj) {
      i32x4 b0 = *(const i32x4*)(B0 + boff[0][jj]);
      i32x4 b1 = *(const i32x4*)(B0 + boff[1][jj]);
#pragma unroll
      for (int i = 0; i < 4; ++i) {
        i32x4 zero = {0, 0, 0, 0};
        i32x4 ic = __builtin_amdgcn_mfma_i32_16x16x64_i8(a[i][0], b0, zero, 0, 0, 0);
        ic = __builtin_amdgcn_mfma_i32_16x16x64_i8(a[i][1], b1, ic, 0, 0, 0);
        float ps = sxq[i] * sn[jj];
        f32x2 p2 = {ps, ps};
        f32x2 c01 = {(float)ic[0], (float)ic[1]};
        f32x2 c23 = {(float)ic[2], (float)ic[3]};
        fc[i][jj][0] = __builtin_elementwise_fma(c01, p2, fc[i][jj][0]);
        fc[i][jj][1] = __builtin_elementwise_fma(c23, p2, fc[i][jj][1]);
      }
    }
    __builtin_amdgcn_s_setprio(0);
    cur ^= 1;
  }

  float bj[4];
#pragma unroll
  for (int jj = 0; jj < 4; ++jj) bj[jj] = bias[n0 + wc + jj * 16 + l16];

#pragma unroll
  for (int i = 0; i < 4; ++i)
#pragma unroll
    for (int jj = 0; jj < 4; ++jj)
#pragma unroll
      for (int r = 0; r < 4; ++r) {
        int m = m0 + wr + i * 16 + quad * 4 + r;
        int n = n0 + wc + jj * 16 + l16;
        out[(size_t)m * 3072 + n] = fc[i][jj][r >> 1][r & 1] + bj[jj];
      }
}

extern "C" void kernel_launch(void* const* d_in, const int* in_sizes, int n_in,
                              void* d_out, int out_size, void* d_ws, size_t ws_size,
                              hipStream_t stream) {
  const float* x        = (const float*)d_in[0];
  const int*   gup_qw   = (const int*)d_in[1];
  const int*   gup_qz   = (const int*)d_in[2];
  const float* gup_sc   = (const float*)d_in[3];
  const int*   down_qw  = (const int*)d_in[4];
  const int*   down_qz  = (const int*)d_in[5];
  const float* down_sc  = (const float*)d_in[6];
  const float* down_b   = (const float*)d_in[7];
  float* out = (float*)d_out;

  char* ws = (char*)d_ws;
  signed char* Xq    = (signed char*)(ws);                 // 12,582,912
  signed char* Wgupq = (signed char*)(ws + 12582912);      // 50,331,648
  signed char* Wdnq  = (signed char*)(ws + 62914560);      // 25,165,824
  signed char* Actq  = (signed char*)(ws + 88080384);      // 33,554,432
  float* Xs4 = (float*)(ws + 121634816);                   // 24x1024
  float* GsT = (float*)(ws + 121733120);                   // 24x16384
  float* DsT = (float*)(ws + 123305984);                   // 64x3072
  float* As4 = (float*)(ws + 124092416);                   // 64x1024

  quant_x<<<dim3(24, 1024), 256, 0, stream>>>(x, Xq, Xs4);
  requant_k<3072><<<24576, 256, 0, stream>>>(gup_qw, gup_qz, Wgupq);
  requant_k<8192><<<12288, 256, 0, stream>>>(down_qw, down_qz, Wdnq);
  transpose_sc<<<1536, 256, 0, stream>>>(gup_sc, GsT, 16384, 24);
  transpose_sc<<<768, 256, 0, stream>>>(down_sc, DsT, 3072, 64);
  gemm_gateup_i8<<<2048, 512, 0, stream>>>(Xq, Wgupq, Xs4, GsT, Actq, As4);
  gemm_down_i8<<<768, 256, 0, stream>>>(Actq, Wdnq, As4, DsT, down_b, out);
}

// Round 2
// 907.007 us; speedup vs baseline: 1.0564x; 1.0564x over previous
//
#include <hip/hip_runtime.h>

// Phi3 quantized MLP on MI355X (gfx950) — R7: dbuf rotation with drain-free ordering.
// R6 post-mortem: stage-issue BEFORE the fragment ds_reads made the compiler's
// may-alias waitcnt pass insert s_waitcnt vmcnt(0) before the ds_reads, draining the
// just-issued next-tile loads every step (MfmaUtil 20%, 432 us). R7 ordering per step:
//   vmcnt(0)+s_barrier  (drains stage issued one full MFMA phase ago)
//   -> ALL fragment ds_reads + scale loads
//   -> sched_barrier -> stage-issue(next tile) -> sched_barrier
//   -> setprio(1) MFMA+rescale setprio(0)
// Compiler-inserted vmcnt(0) before ds_reads now covers only already-drained loads
// (free); no LDS reads exist between stage-issue and the next-iter top, so the stage
// loads stay in flight across the whole MFMA cluster. g-loop unrolled x2 so both
// buffer bases are compile-time constants. Math identical to R5/R6.

typedef float f32x4 __attribute__((ext_vector_type(4)));
typedef float f32x2 __attribute__((ext_vector_type(2)));
typedef int   i32x4 __attribute__((ext_vector_type(4)));

__device__ __forceinline__ void gload16(const void* g, void* l) {
  __builtin_amdgcn_global_load_lds(
      (const __attribute__((address_space(1))) void*)g,
      (__attribute__((address_space(3))) void*)l, 16, 0, 0);
}

// ---------------- quantize x: f32 -> int8, scale per (row-quad of 4, group of 128) ----------------
__global__ __launch_bounds__(256) void quant_x(const float* __restrict__ x,
                                               signed char* __restrict__ Xq,
                                               float* __restrict__ Xs4) {
  int g    = blockIdx.x;
  int rq   = blockIdx.y;
  int w    = threadIdx.x >> 6;
  int lane = threadIdx.x & 63;
  int row  = rq * 4 + w;
  __shared__ float wmax[4];
  const float2 v = *(const float2*)(x + (size_t)row * 3072 + g * 128 + lane * 2);
  float m = fmaxf(fabsf(v.x), fabsf(v.y));
#pragma unroll
  for (int s = 1; s < 64; s <<= 1) m = fmaxf(m, __shfl_xor(m, s));
  if (lane == 0) wmax[w] = m;
  __syncthreads();
  float m4 = fmaxf(fmaxf(wmax[0], wmax[1]), fmaxf(wmax[2], wmax[3]));
  float inv = m4 > 0.f ? 127.f / m4 : 0.f;
  int qa = (int)rintf(v.x * inv);
  int qb = (int)rintf(v.y * inv);
  unsigned short pk = (unsigned short)((qa & 0xff) | ((qb & 0xff) << 8));
  *(unsigned short*)(Xq + (size_t)row * 3072 + g * 128 + lane * 2) = pk;
  if (threadIdx.x == 0) Xs4[g * 1024 + rq] = m4 * (1.f / 127.f);
}

// ---------------- requant weights: int32 q,z -> int8 (q - z), exact ----------------
template <int K>
__global__ __launch_bounds__(256) void requant_k(const int* __restrict__ qw,
                                                 const int* __restrict__ qz,
                                                 signed char* __restrict__ W) {
  constexpr int KG = K / 128;
  constexpr int perrow = K / 8;
  int idx = blockIdx.x * 256 + threadIdx.x;
  int row = idx / perrow;
  int c8  = idx - row * perrow;
  int k   = c8 << 3;
  int z   = qz[row * KG + (k >> 7)];
  const int4* q4 = (const int4*)(qw + (size_t)row * K + k);
  int4 qa = q4[0];
  int4 qb = q4[1];
  int b0 = ((qa.x - z) & 0xff) | (((qa.y - z) & 0xff) << 8) |
           (((qa.z - z) & 0xff) << 16) | (((qa.w - z) & 0xff) << 24);
  int b1 = ((qb.x - z) & 0xff) | (((qb.y - z) & 0xff) << 8) |
           (((qb.z - z) & 0xff) << 16) | (((qb.w - z) & 0xff) << 24);
  int2 o; o.x = b0; o.y = b1;
  *(int2*)(W + (size_t)row * K + k) = o;
}

// ---------------- scale transpose: [R][G] -> [G][R] ----------------
__global__ __launch_bounds__(256) void transpose_sc(const float* __restrict__ in,
                                                    float* __restrict__ out,
                                                    int R, int G) {
  int idx = blockIdx.x * 256 + threadIdx.x;
  int r = idx / G;
  int g = idx - r * G;
  out[(size_t)g * R + r] = in[idx];
}

// LDS tile: 128 rows x 128 bytes, XOR-swizzled (phys chunk p holds logical p^(row&7)).

// ---------------- GEMM1: act = silu(x@Wg^T)*(x@Wu^T), int8 in, int8 out ----------------
// 512 threads, 8 waves in a 2(M)x4(N) grid; per-wave 64x32 of both gate and up.
// Double-buffered A/G/U tiles (2 x 48 KB), drain-free rotation pipeline.

#define GUP_STEP(RB, WB, G, DO_STAGE)                                              \
  {                                                                                \
    asm volatile("s_waitcnt vmcnt(0)" ::: "memory");                               \
    __builtin_amdgcn_s_barrier();                                                  \
    __builtin_amdgcn_sched_barrier(0);                                             \
    const signed char* Ab = smem + (RB);                                           \
    const signed char* Gb = Ab + 16384;                                            \
    const signed char* Ub = Ab + 32768;                                            \
    i32x4 a[4][2];                                                                 \
    i32x4 bg[2][2];                                                                \
    i32x4 bu[2][2];                                                                \
    _Pragma("unroll") for (int i = 0; i < 4; ++i) {                                \
      a[i][0] = *(const i32x4*)(Ab + aoff[0][i]);                                  \
      a[i][1] = *(const i32x4*)(Ab + aoff[1][i]);                                  \
    }                                                                              \
    _Pragma("unroll") for (int jj = 0; jj < 2; ++jj) {                             \
      bg[jj][0] = *(const i32x4*)(Gb + boff[0][jj]);                               \
      bg[jj][1] = *(const i32x4*)(Gb + boff[1][jj]);                               \
      bu[jj][0] = *(const i32x4*)(Ub + boff[0][jj]);                               \
      bu[jj][1] = *(const i32x4*)(Ub + boff[1][jj]);                               \
    }                                                                              \
    float sxq[4], sg[2], su[2];                                                    \
    _Pragma("unroll") for (int i = 0; i < 4; ++i)                                  \
      sxq[i] = Xs4[(G) * 1024 + qbase + i * 4];                                    \
    _Pragma("unroll") for (int jj = 0; jj < 2; ++jj) {                             \
      sg[jj] = GsT[(G) * 16384 + n0 + wc + jj * 16 + l16];                         \
      su[jj] = GsT[(G) * 16384 + 8192 + n0 + wc + jj * 16 + l16];                  \
    }                                                                              \
    __builtin_amdgcn_sched_barrier(0);                                             \
    if (DO_STAGE) {                                                                \
      const int kk = ((G) + 1) << 7;                                               \
      _Pragma("unroll") for (int t = 0; t < 2; ++t) {                              \
        gload16(baseA + off[t] + kk, smem + (WB) + (tid + 512 * t) * 16);          \
        gload16(baseG + off[t] + kk, smem + (WB) + 16384 + (tid + 512 * t) * 16);  \
        gload16(baseU + off[t] + kk, smem + (WB) + 32768 + (tid + 512 * t) * 16);  \
      }                                                                            \
    }                                                                              \
    __builtin_amdgcn_sched_barrier(0);                                             \
    __builtin_amdgcn_s_setprio(1);                                                 \
    _Pragma("unroll") for (int jj = 0; jj < 2; ++jj) {                             \
      _Pragma("unroll") for (int i = 0; i < 4; ++i) {                              \
        i32x4 zero = {0, 0, 0, 0};                                                 \
        i32x4 ig = __builtin_amdgcn_mfma_i32_16x16x64_i8(a[i][0], bg[jj][0], zero, 0, 0, 0); \
        ig = __builtin_amdgcn_mfma_i32_16x16x64_i8(a[i][1], bg[jj][1], ig, 0, 0, 0); \
        i32x4 iu = __builtin_amdgcn_mfma_i32_16x16x64_i8(a[i][0], bu[jj][0], zero, 0, 0, 0); \
        iu = __builtin_amdgcn_mfma_i32_16x16x64_i8(a[i][1], bu[jj][1], iu, 0, 0, 0); \
        float pgs = sxq[i] * sg[jj];                                               \
        float pus = sxq[i] * su[jj];                                               \
        f32x2 pg2 = {pgs, pgs};                                                    \
        f32x2 pu2 = {pus, pus};                                                    \
        f32x2 g01 = {(float)ig[0], (float)ig[1]};                                  \
        f32x2 g23 = {(float)ig[2], (float)ig[3]};                                  \
        f32x2 u01 = {(float)iu[0], (float)iu[1]};                                  \
        f32x2 u23 = {(float)iu[2], (float)iu[3]};                                  \
        fg[i][jj][0] = __builtin_elementwise_fma(g01, pg2, fg[i][jj][0]);          \
        fg[i][jj][1] = __builtin_elementwise_fma(g23, pg2, fg[i][jj][1]);          \
        fu[i][jj][0] = __builtin_elementwise_fma(u01, pu2, fu[i][jj][0]);          \
        fu[i][jj][1] = __builtin_elementwise_fma(u23, pu2, fu[i][jj][1]);          \
      }                                                                            \
    }                                                                              \
    __builtin_amdgcn_s_setprio(0);                                                 \
  }

__global__ __launch_bounds__(512, 2) void gemm_gateup_i8(
    const signed char* __restrict__ Xq, const signed char* __restrict__ Wq,
    const float* __restrict__ Xs4,   // [24][1024]
    const float* __restrict__ GsT,   // [24][16384]
    signed char* __restrict__ act,   // [4096][8192]
    float* __restrict__ As4) {       // [64][1024]
  const int K = 3072;
  const int bid = blockIdx.x;
  const int xcd = bid & 7;
  const int jb  = bid >> 3;
  const int n0  = ((xcd << 3) + (jb & 7)) * 128;
  const int m0  = (jb >> 3) * 128;
  __shared__ __align__(16) signed char smem[98304];   // [2][A 16K | G 16K | U 16K]
  __shared__ float rmax[4][128];
  __shared__ float rmax4[32];

  const int tid  = threadIdx.x;
  const int l    = tid & 63;
  const int quad = l >> 4;
  const int l16  = l & 15;
  const int w    = tid >> 6;
  const int wr   = (w >> 2) * 64;   // 0 or 64
  const int wc   = (w & 3) * 32;    // 0,32,64,96

  f32x2 fg[4][2][2] = {};
  f32x2 fu[4][2][2] = {};

  int off[2];
#pragma unroll
  for (int t = 0; t < 2; ++t) {
    int c   = tid + 512 * t;
    int row = c >> 3;
    int log = (c & 7) ^ (row & 7);
    off[t] = row * K + log * 16;
  }
  const signed char* baseA = Xq + (size_t)m0 * K;
  const signed char* baseG = Wq + (size_t)n0 * K;
  const signed char* baseU = Wq + (size_t)(8192 + n0) * K;

  int aoff[2][4], boff[2][2];
#pragma unroll
  for (int h = 0; h < 2; ++h) {
    int slot = h * 4 + quad;
#pragma unroll
    for (int i = 0; i < 4; ++i) {
      int ra = wr + i * 16 + l16;
      aoff[h][i] = ra * 128 + ((slot ^ (ra & 7)) * 16);
    }
#pragma unroll
    for (int jj = 0; jj < 2; ++jj) {
      int rb = wc + jj * 16 + l16;
      boff[h][jj] = rb * 128 + ((slot ^ (rb & 7)) * 16);
    }
  }
  const int qbase = (m0 >> 2) + (wr >> 2) + quad;

  // prologue: stage tile 0 into half 0
#pragma unroll
  for (int t = 0; t < 2; ++t) {
    gload16(baseA + off[t], smem + (tid + 512 * t) * 16);
    gload16(baseG + off[t], smem + 16384 + (tid + 512 * t) * 16);
    gload16(baseU + off[t], smem + 32768 + (tid + 512 * t) * 16);
  }

#pragma unroll 1
  for (int gg = 0; gg < 24; gg += 2) {
    GUP_STEP(0, 49152, gg, true)
    GUP_STEP(49152, 0, gg + 1, gg < 22)
  }

  // ---- epilogue: silu(g)*u -> quad-shared absmax -> int8 ----
  float av[4][2][4];   // [i][jj][r]
#pragma unroll
  for (int i = 0; i < 4; ++i)
#pragma unroll
    for (int jj = 0; jj < 2; ++jj)
#pragma unroll
      for (int r = 0; r < 4; ++r) {
        float gv = fg[i][jj][r >> 1][r & 1];
        float uv = fu[i][jj][r >> 1][r & 1];
        av[i][jj][r] = (gv / (1.f + __expf(-gv))) * uv;
      }

#pragma unroll
  for (int i = 0; i < 4; ++i)
#pragma unroll
    for (int r = 0; r < 4; ++r) {
      float m = fmaxf(fabsf(av[i][0][r]), fabsf(av[i][1][r]));
      m = fmaxf(m, __shfl_xor(m, 1));
      m = fmaxf(m, __shfl_xor(m, 2));
      m = fmaxf(m, __shfl_xor(m, 4));
      m = fmaxf(m, __shfl_xor(m, 8));
      if (l16 == 0) rmax[w & 3][wr + i * 16 + quad * 4 + r] = m;
    }
  __syncthreads();
  if (tid < 32) {
    float m = 0.f;
#pragma unroll
    for (int c = 0; c < 4; ++c)
#pragma unroll
      for (int k = 0; k < 4; ++k) m = fmaxf(m, rmax[c][tid * 4 + k]);
    rmax4[tid] = m;
    As4[(n0 >> 7) * 1024 + (m0 >> 2) + tid] = m * (1.f / 127.f);
  }
  __syncthreads();

#pragma unroll
  for (int i = 0; i < 4; ++i) {
    float mx = rmax4[(wr >> 2) + i * 4 + quad];
    float inv = mx > 0.f ? 127.f / mx : 0.f;
#pragma unroll
    for (int r = 0; r < 4; ++r) {
      int mrow = wr + i * 16 + quad * 4 + r;
#pragma unroll
      for (int jj = 0; jj < 2; ++jj) {
        int q = (int)rintf(av[i][jj][r] * inv);
        smem[mrow * 128 + wc + jj * 16 + l16] = (signed char)q;
      }
    }
  }
  __syncthreads();

#pragma unroll
  for (int t = 0; t < 2; ++t) {
    int c = tid + 512 * t;
    int row = c >> 3;
    int col = (c & 7) * 16;
    *(int4*)(act + (size_t)(m0 + row) * 8192 + n0 + col) = *(const int4*)(smem + row * 128 + col);
  }
}

// ---------------- GEMM2: out = dequant(act)@Wd^T + bias ----------------
// 256 threads, double-buffered A/B tiles (2 x 32 KB -> 2 blocks/CU), drain-free rotation.

#define DN_STEP(RB, WB, G, DO_STAGE)                                               \
  {                                                                                \
    asm volatile("s_waitcnt vmcnt(0)" ::: "memory");                               \
    __builtin_amdgcn_s_barrier();                                                  \
    __builtin_amdgcn_sched_barrier(0);                                             \
    const signed char* Ab = smem + (RB);                                           \
    const signed char* Bb = Ab + 16384;                                            \
    i32x4 a[4][2];                                                                 \
    i32x4 b[4][2];                                                                 \
    _Pragma("unroll") for (int i = 0; i < 4; ++i) {                                \
      a[i][0] = *(const i32x4*)(Ab + aoff[0][i]);                                  \
      a[i][1] = *(const i32x4*)(Ab + aoff[1][i]);                                  \
    }                                                                              \
    _Pragma("unroll") for (int jj = 0; jj < 4; ++jj) {                             \
      b[jj][0] = *(const i32x4*)(Bb + boff[0][jj]);                                \
      b[jj][1] = *(const i32x4*)(Bb + boff[1][jj]);                                \
    }                                                                              \
    float sxq[4], sn[4];                                                           \
    _Pragma("unroll") for (int i = 0; i < 4; ++i)                                  \
      sxq[i] = As4[(G) * 1024 + qbase + i * 4];                                    \
    _Pragma("unroll") for (int jj = 0; jj < 4; ++jj)                               \
      sn[jj] = DsT[(G) * 3072 + n0 + wc + jj * 16 + l16];                          \
    __builtin_amdgcn_sched_barrier(0);                                             \
    if (DO_STAGE) {                                                                \
      const int kk = ((G) + 1) << 7;                                               \
      _Pragma("unroll") for (int t = 0; t < 4; ++t) {                              \
        gload16(baseA + off[t] + kk, smem + (WB) + (tid + 256 * t) * 16);          \
        gload16(baseB + off[t] + kk, smem + (WB) + 16384 + (tid + 256 * t) * 16);  \
      }                                                                            \
    }                                                                              \
    __builtin_amdgcn_sched_barrier(0);                                             \
    __builtin_amdgcn_s_setprio(1);                                                 \
    _Pragma("unroll") for (int jj = 0; jj < 4; ++jj) {                             \
      _Pragma("unroll") for (int i = 0; i < 4; ++i) {                              \
        i32x4 zero = {0, 0, 0, 0};                                                 \
        i32x4 ic = __builtin_amdgcn_mfma_i32_16x16x64_i8(a[i][0], b[jj][0], zero, 0, 0, 0); \
        ic = __builtin_amdgcn_mfma_i32_16x16x64_i8(a[i][1], b[jj][1], ic, 0, 0, 0); \
        float ps = sxq[i] * sn[jj];                                                \
        f32x2 p2 = {ps, ps};                                                       \
        f32x2 c01 = {(float)ic[0], (float)ic[1]};                                  \
        f32x2 c23 = {(float)ic[2], (float)ic[3]};                                  \
        fc[i][jj][0] = __builtin_elementwise_fma(c01, p2, fc[i][jj][0]);           \
        fc[i][jj][1] = __builtin_elementwise_fma(c23, p2, fc[i][jj][1]);           \
      }                                                                            \
    }                                                                              \
    __builtin_amdgcn_s_setprio(0);                                                 \
  }

__global__ __launch_bounds__(256, 2) void gemm_down_i8(
    const signed char* __restrict__ Aq, const signed char* __restrict__ Wq,
    const float* __restrict__ As4,   // [64][1024]
    const float* __restrict__ DsT,   // [64][3072]
    const float* __restrict__ bias,
    float* __restrict__ out) {
  const int K = 8192;
  const int bid = blockIdx.x;
  const int xcd = bid & 7;
  const int jb  = bid >> 3;
  const int jn  = jb % 12;
  const int jm  = jb / 12;
  const int n0  = (12 * (xcd & 1) + jn) * 128;
  const int m0  = (8 * (xcd >> 1) + jm) * 128;
  __shared__ __align__(16) signed char smem[65536];   // [2][A 16K | B 16K]

  const int tid  = threadIdx.x;
  const int l    = tid & 63;
  const int quad = l >> 4;
  const int l16  = l & 15;
  const int wr   = ((tid >> 6) >> 1) * 64;
  const int wc   = ((tid >> 6) & 1) * 64;

  f32x2 fc[4][4][2] = {};

  int off[4];
#pragma unroll
  for (int jj = 0; jj < 4; ++jj) {
    int c   = tid + 256 * jj;
    int row = c >> 3;
    int log = (c & 7) ^ (row & 7);
    off[jj] = row * K + log * 16;
  }
  const signed char* baseA = Aq + (size_t)m0 * K;
  const signed char* baseB = Wq + (size_t)n0 * K;

  int aoff[2][4], boff[2][4];
#pragma unroll
  for (int h = 0; h < 2; ++h) {
    int slot = h * 4 + quad;
#pragma unroll
    for (int i = 0; i < 4; ++i) {
      int ra = wr + i * 16 + l16;
      aoff[h][i] = ra * 128 + ((slot ^ (ra & 7)) * 16);
      int rb = wc + i * 16 + l16;
      boff[h][i] = rb * 128 + ((slot ^ (rb & 7)) * 16);
    }
  }
  const int qbase = (m0 >> 2) + (wr >> 2) + quad;

  // prologue: stage tile 0 into half 0
#pragma unroll
  for (int jj = 0; jj < 4; ++jj) {
    gload16(baseA + off[jj], smem + (tid + 256 * jj) * 16);
    gload16(baseB + off[jj], smem + 16384 + (tid + 256 * jj) * 16);
  }

#pragma unroll 1
  for (int gg = 0; gg < 64; gg += 2) {
    DN_STEP(0, 32768, gg, true)
    DN_STEP(32768, 0, gg + 1, gg < 62)
  }

  float bj[4];
#pragma unroll
  for (int jj = 0; jj < 4; ++jj) bj[jj] = bias[n0 + wc + jj * 16 + l16];

#pragma unroll
  for (int i = 0; i < 4; ++i)
#pragma unroll
    for (int jj = 0; jj < 4; ++jj)
#pragma unroll
      for (int r = 0; r < 4; ++r) {
        int m = m0 + wr + i * 16 + quad * 4 + r;
        int n = n0 + wc + jj * 16 + l16;
        out[(size_t)m * 3072 + n] = fc[i][jj][r >> 1][r & 1] + bj[jj];
      }
}

extern "C" void kernel_launch(void* const* d_in, const int* in_sizes, int n_in,
                              void* d_out, int out_size, void* d_ws, size_t ws_size,
                              hipStream_t stream) {
  const float* x        = (const float*)d_in[0];
  const int*   gup_qw   = (const int*)d_in[1];
  const int*   gup_qz   = (const int*)d_in[2];
  const float* gup_sc   = (const float*)d_in[3];
  const int*   down_qw  = (const int*)d_in[4];
  const int*   down_qz  = (const int*)d_in[5];
  const float* down_sc  = (const float*)d_in[6];
  const float* down_b   = (const float*)d_in[7];
  float* out = (float*)d_out;

  char* ws = (char*)d_ws;
  signed char* Xq    = (signed char*)(ws);                 // 12,582,912
  signed char* Wgupq = (signed char*)(ws + 12582912);      // 50,331,648
  signed char* Wdnq  = (signed char*)(ws + 62914560);      // 25,165,824
  signed char* Actq  = (signed char*)(ws + 88080384);      // 33,554,432
  float* Xs4 = (float*)(ws + 121634816);                   // 24x1024
  float* GsT = (float*)(ws + 121733120);                   // 24x16384
  float* DsT = (float*)(ws + 123305984);                   // 64x3072
  float* As4 = (float*)(ws + 124092416);                   // 64x1024

  quant_x<<<dim3(24, 1024), 256, 0, stream>>>(x, Xq, Xs4);
  requant_k<3072><<<24576, 256, 0, stream>>>(gup_qw, gup_qz, Wgupq);
  requant_k<8192><<<12288, 256, 0, stream>>>(down_qw, down_qz, Wdnq);
  transpose_sc<<<1536, 256, 0, stream>>>(gup_sc, GsT, 16384, 24);
  transpose_sc<<<768, 256, 0, stream>>>(down_sc, DsT, 3072, 64);
  gemm_gateup_i8<<<2048, 512, 0, stream>>>(Xq, Wgupq, Xs4, GsT, Actq, As4);
  gemm_down_i8<<<768, 256, 0, stream>>>(Actq, Wdnq, As4, DsT, down_b, out);
}

// Round 3
// 807.732 us; speedup vs baseline: 1.1863x; 1.1229x over previous
//
#include <hip/hip_runtime.h>

// Phi3 quantized MLP on MI355X (gfx950) — R8: R5 base + n-major block cohorts + setprio.
// R6/R7 post-mortem: dbuf pipelines ran at the SAME 8 waves/CU as R5 but FETCH rose
// 152->252 MB (+140 us at 700 GB/s) — L2 thrash, not occupancy, was the regression.
// Old mapping (n-fastest per XCD) keeps 8 weight n-panels (6 MB) live against a 4 MB
// per-XCD L2. R8 reverts to the proven R5 single-buffer structure (per-step drain is
// only ~17 us total) and makes block order n-MAJOR per XCD: 32 consecutive blocks
// share one n-panel (resident window = 2 panels x 32 m = 1.5 MB -> L2-fit, weights
// fetched ~once from HBM). Same cohort scheme for gemm_down. Plus s_setprio(1) around
// the MFMA cluster (2 co-resident blocks are phase-desynced -> arbitration helps).

typedef float f32x4 __attribute__((ext_vector_type(4)));
typedef float f32x2 __attribute__((ext_vector_type(2)));
typedef int   i32x4 __attribute__((ext_vector_type(4)));

__device__ __forceinline__ void gload16(const void* g, void* l) {
  __builtin_amdgcn_global_load_lds(
      (const __attribute__((address_space(1))) void*)g,
      (__attribute__((address_space(3))) void*)l, 16, 0, 0);
}

// ---------------- quantize x: f32 -> int8, scale per (row-quad of 4, group of 128) ----------------
// grid (24, 1024): g = blockIdx.x, row-quad = blockIdx.y. Xs4: [24][1024]
__global__ __launch_bounds__(256) void quant_x(const float* __restrict__ x,
                                               signed char* __restrict__ Xq,
                                               float* __restrict__ Xs4) {
  int g    = blockIdx.x;
  int rq   = blockIdx.y;
  int w    = threadIdx.x >> 6;
  int lane = threadIdx.x & 63;
  int row  = rq * 4 + w;
  __shared__ float wmax[4];
  const float2 v = *(const float2*)(x + (size_t)row * 3072 + g * 128 + lane * 2);
  float m = fmaxf(fabsf(v.x), fabsf(v.y));
#pragma unroll
  for (int s = 1; s < 64; s <<= 1) m = fmaxf(m, __shfl_xor(m, s));
  if (lane == 0) wmax[w] = m;
  __syncthreads();
  float m4 = fmaxf(fmaxf(wmax[0], wmax[1]), fmaxf(wmax[2], wmax[3]));
  float inv = m4 > 0.f ? 127.f / m4 : 0.f;
  int qa = (int)rintf(v.x * inv);
  int qb = (int)rintf(v.y * inv);
  unsigned short pk = (unsigned short)((qa & 0xff) | ((qb & 0xff) << 8));
  *(unsigned short*)(Xq + (size_t)row * 3072 + g * 128 + lane * 2) = pk;
  if (threadIdx.x == 0) Xs4[g * 1024 + rq] = m4 * (1.f / 127.f);
}

// ---------------- requant weights: int32 q,z -> int8 (q - z), exact ----------------
template <int K>
__global__ __launch_bounds__(256) void requant_k(const int* __restrict__ qw,
                                                 const int* __restrict__ qz,
                                                 signed char* __restrict__ W) {
  constexpr int KG = K / 128;
  constexpr int perrow = K / 8;
  int idx = blockIdx.x * 256 + threadIdx.x;
  int row = idx / perrow;
  int c8  = idx - row * perrow;
  int k   = c8 << 3;
  int z   = qz[row * KG + (k >> 7)];
  const int4* q4 = (const int4*)(qw + (size_t)row * K + k);
  int4 qa = q4[0];
  int4 qb = q4[1];
  int b0 = ((qa.x - z) & 0xff) | (((qa.y - z) & 0xff) << 8) |
           (((qa.z - z) & 0xff) << 16) | (((qa.w - z) & 0xff) << 24);
  int b1 = ((qb.x - z) & 0xff) | (((qb.y - z) & 0xff) << 8) |
           (((qb.z - z) & 0xff) << 16) | (((qb.w - z) & 0xff) << 24);
  int2 o; o.x = b0; o.y = b1;
  *(int2*)(W + (size_t)row * K + k) = o;
}

// ---------------- scale transpose: [R][G] -> [G][R] ----------------
__global__ __launch_bounds__(256) void transpose_sc(const float* __restrict__ in,
                                                    float* __restrict__ out,
                                                    int R, int G) {
  int idx = blockIdx.x * 256 + threadIdx.x;
  int r = idx / G;
  int g = idx - r * G;
  out[(size_t)g * R + r] = in[idx];
}

// LDS tile: 128 rows x 128 bytes, XOR-swizzled (phys chunk p holds logical p^(row&7)).

// ---------------- GEMM1: act = silu(x@Wg^T)*(x@Wu^T), int8 in, int8 out ----------------
__global__ __launch_bounds__(256, 2) void gemm_gateup_i8(
    const signed char* __restrict__ Xq, const signed char* __restrict__ Wq,
    const float* __restrict__ Xs4,   // [24][1024]
    const float* __restrict__ GsT,   // [24][16384]
    signed char* __restrict__ act,   // [4096][8192]
    float* __restrict__ As4) {       // [64][1024]
  const int K = 3072;
  const int bid = blockIdx.x;
  // n-major cohorts per XCD: 32 consecutive blocks on one XCD share one n-panel.
  const int xcd = bid & 7;
  const int j   = bid >> 3;                     // 0..255
  const int n0  = ((xcd << 3) + (j >> 5)) * 128;  // 64 n-panels, 8 per XCD
  const int m0  = (j & 31) * 128;                 // 32 m-panels, n-major order
  __shared__ signed char lA[16384];
  __shared__ signed char lG[16384];
  __shared__ signed char lU[16384];
  __shared__ float rmax[2][128];
  __shared__ float rmax4[32];

  const int tid  = threadIdx.x;
  const int l    = tid & 63;
  const int quad = l >> 4;
  const int l16  = l & 15;
  const int wcI  = (tid >> 6) & 1;
  const int wr   = ((tid >> 6) >> 1) * 64;
  const int wc   = wcI * 64;

  f32x2 fg[4][4][2] = {};
  f32x2 fu[4][4][2] = {};

  int off[4];
#pragma unroll
  for (int jj = 0; jj < 4; ++jj) {
    int c   = tid + 256 * jj;
    int row = c >> 3;
    int log = (c & 7) ^ (row & 7);
    off[jj] = row * K + log * 16;
  }
  const signed char* baseA = Xq + (size_t)m0 * K;
  const signed char* baseG = Wq + (size_t)n0 * K;
  const signed char* baseU = Wq + (size_t)(8192 + n0) * K;

  int aoff[2][4], boff[2][4];
#pragma unroll
  for (int h = 0; h < 2; ++h) {
    int slot = h * 4 + quad;
#pragma unroll
    for (int i = 0; i < 4; ++i) {
      int ra = wr + i * 16 + l16;
      aoff[h][i] = ra * 128 + ((slot ^ (ra & 7)) * 16);
      int rb = wc + i * 16 + l16;
      boff[h][i] = rb * 128 + ((slot ^ (rb & 7)) * 16);
    }
  }
  const int qbase = (m0 >> 2) + (wr >> 2) + quad;   // row-quad index base (i adds i*4)

  for (int g = 0; g < 24; ++g) {
    const int kk = g << 7;
#pragma unroll
    for (int jj = 0; jj < 4; ++jj) {
      gload16(baseA + off[jj] + kk, lA + (tid + 256 * jj) * 16);
      gload16(baseG + off[jj] + kk, lG + (tid + 256 * jj) * 16);
      gload16(baseU + off[jj] + kk, lU + (tid + 256 * jj) * 16);
    }
    float sxq[4], sg[4], su[4];
#pragma unroll
    for (int i = 0; i < 4; ++i) sxq[i] = Xs4[g * 1024 + qbase + i * 4];
#pragma unroll
    for (int jj = 0; jj < 4; ++jj) {
      sg[jj] = GsT[g * 16384 + n0 + wc + jj * 16 + l16];
      su[jj] = GsT[g * 16384 + 8192 + n0 + wc + jj * 16 + l16];
    }
    __syncthreads();

    i32x4 a[4][2];
#pragma unroll
    for (int i = 0; i < 4; ++i) {
      a[i][0] = *(const i32x4*)(lA + aoff[0][i]);
      a[i][1] = *(const i32x4*)(lA + aoff[1][i]);
    }
    __builtin_amdgcn_s_setprio(1);
#pragma unroll
    for (int jj = 0; jj < 4; ++jj) {
      i32x4 bg0 = *(const i32x4*)(lG + boff[0][jj]);
      i32x4 bg1 = *(const i32x4*)(lG + boff[1][jj]);
      i32x4 bu0 = *(const i32x4*)(lU + boff[0][jj]);
      i32x4 bu1 = *(const i32x4*)(lU + boff[1][jj]);
#pragma unroll
      for (int i = 0; i < 4; ++i) {
        i32x4 zero = {0, 0, 0, 0};
        i32x4 ig = __builtin_amdgcn_mfma_i32_16x16x64_i8(a[i][0], bg0, zero, 0, 0, 0);
        ig = __builtin_amdgcn_mfma_i32_16x16x64_i8(a[i][1], bg1, ig, 0, 0, 0);
        i32x4 iu = __builtin_amdgcn_mfma_i32_16x16x64_i8(a[i][0], bu0, zero, 0, 0, 0);
        iu = __builtin_amdgcn_mfma_i32_16x16x64_i8(a[i][1], bu1, iu, 0, 0, 0);
        float pgs = sxq[i] * sg[jj];
        float pus = sxq[i] * su[jj];
        f32x2 pg2 = {pgs, pgs};
        f32x2 pu2 = {pus, pus};
        f32x2 g01 = {(float)ig[0], (float)ig[1]};
        f32x2 g23 = {(float)ig[2], (float)ig[3]};
        f32x2 u01 = {(float)iu[0], (float)iu[1]};
        f32x2 u23 = {(float)iu[2], (float)iu[3]};
        fg[i][jj][0] = __builtin_elementwise_fma(g01, pg2, fg[i][jj][0]);
        fg[i][jj][1] = __builtin_elementwise_fma(g23, pg2, fg[i][jj][1]);
        fu[i][jj][0] = __builtin_elementwise_fma(u01, pu2, fu[i][jj][0]);
        fu[i][jj][1] = __builtin_elementwise_fma(u23, pu2, fu[i][jj][1]);
      }
    }
    __builtin_amdgcn_s_setprio(0);
    __syncthreads();
  }

  // ---- epilogue: silu(g)*u -> quad-shared absmax -> int8 ----
  float av[4][4][4];   // [i][jj][r]
#pragma unroll
  for (int i = 0; i < 4; ++i)
#pragma unroll
    for (int jj = 0; jj < 4; ++jj)
#pragma unroll
      for (int r = 0; r < 4; ++r) {
        float gv = fg[i][jj][r >> 1][r & 1];
        float uv = fu[i][jj][r >> 1][r & 1];
        av[i][jj][r] = (gv / (1.f + __expf(-gv))) * uv;
      }

#pragma unroll
  for (int i = 0; i < 4; ++i)
#pragma unroll
    for (int r = 0; r < 4; ++r) {
      float m = 0.f;
#pragma unroll
      for (int jj = 0; jj < 4; ++jj) m = fmaxf(m, fabsf(av[i][jj][r]));
      m = fmaxf(m, __shfl_xor(m, 1));
      m = fmaxf(m, __shfl_xor(m, 2));
      m = fmaxf(m, __shfl_xor(m, 4));
      m = fmaxf(m, __shfl_xor(m, 8));
      if (l16 == 0) rmax[wcI][wr + i * 16 + quad * 4 + r] = m;
    }
  __syncthreads();
  if (tid < 32) {
    float m = 0.f;
#pragma unroll
    for (int k = 0; k < 4; ++k)
      m = fmaxf(m, fmaxf(rmax[0][tid * 4 + k], rmax[1][tid * 4 + k]));
    rmax4[tid] = m;
    As4[(n0 >> 7) * 1024 + (m0 >> 2) + tid] = m * (1.f / 127.f);
  }
  __syncthreads();

#pragma unroll
  for (int i = 0; i < 4; ++i) {
    float mx = rmax4[(wr >> 2) + i * 4 + quad];
    float inv = mx > 0.f ? 127.f / mx : 0.f;
#pragma unroll
    for (int r = 0; r < 4; ++r) {
      int mrow = wr + i * 16 + quad * 4 + r;
#pragma unroll
      for (int jj = 0; jj < 4; ++jj) {
        int q = (int)rintf(av[i][jj][r] * inv);
        lA[mrow * 128 + wc + jj * 16 + l16] = (signed char)q;
      }
    }
  }
  __syncthreads();

#pragma unroll
  for (int t = 0; t < 4; ++t) {
    int c = tid + 256 * t;
    int row = c >> 3;
    int col = (c & 7) * 16;
    *(int4*)(act + (size_t)(m0 + row) * 8192 + n0 + col) = *(const int4*)(lA + row * 128 + col);
  }
}

// ---------------- GEMM2: out = dequant(act)@Wd^T + bias ----------------
__global__ __launch_bounds__(256, 2) void gemm_down_i8(
    const signed char* __restrict__ Aq, const signed char* __restrict__ Wq,
    const float* __restrict__ As4,   // [64][1024]
    const float* __restrict__ DsT,   // [64][3072]
    const float* __restrict__ bias,
    float* __restrict__ out) {
  const int K = 8192;
  const int bid = blockIdx.x;
  // n-major cohorts per XCD: 3 n-panels per XCD, 32 m-blocks per panel.
  const int xcd = bid & 7;
  const int j   = bid >> 3;                 // 0..95
  const int n0  = (xcd * 3 + (j >> 5)) * 128;   // 24 n-panels
  const int m0  = (j & 31) * 128;               // 32 m-panels, n-major order
  __shared__ signed char lA[16384];
  __shared__ signed char lB[16384];

  const int tid  = threadIdx.x;
  const int l    = tid & 63;
  const int quad = l >> 4;
  const int l16  = l & 15;
  const int wr   = ((tid >> 6) >> 1) * 64;
  const int wc   = ((tid >> 6) & 1) * 64;

  f32x2 fc[4][4][2] = {};

  int off[4];
#pragma unroll
  for (int jj = 0; jj < 4; ++jj) {
    int c   = tid + 256 * jj;
    int row = c >> 3;
    int log = (c & 7) ^ (row & 7);
    off[jj] = row * K + log * 16;
  }
  const signed char* baseA = Aq + (size_t)m0 * K;
  const signed char* baseB = Wq + (size_t)n0 * K;

  int aoff[2][4], boff[2][4];
#pragma unroll
  for (int h = 0; h < 2; ++h) {
    int slot = h * 4 + quad;
#pragma unroll
    for (int i = 0; i < 4; ++i) {
      int ra = wr + i * 16 + l16;
      aoff[h][i] = ra * 128 + ((slot ^ (ra & 7)) * 16);
      int rb = wc + i * 16 + l16;
      boff[h][i] = rb * 128 + ((slot ^ (rb & 7)) * 16);
    }
  }
  const int qbase = (m0 >> 2) + (wr >> 2) + quad;

  for (int g = 0; g < 64; ++g) {
    const int kk = g << 7;
#pragma unroll
    for (int jj = 0; jj < 4; ++jj) {
      gload16(baseA + off[jj] + kk, lA + (tid + 256 * jj) * 16);
      gload16(baseB + off[jj] + kk, lB + (tid + 256 * jj) * 16);
    }
    float sxq[4], sn[4];
#pragma unroll
    for (int i = 0; i < 4; ++i) sxq[i] = As4[g * 1024 + qbase + i * 4];
#pragma unroll
    for (int jj = 0; jj < 4; ++jj)
      sn[jj] = DsT[g * 3072 + n0 + wc + jj * 16 + l16];
    __syncthreads();

    i32x4 a[4][2];
#pragma unroll
    for (int i = 0; i < 4; ++i) {
      a[i][0] = *(const i32x4*)(lA + aoff[0][i]);
      a[i][1] = *(const i32x4*)(lA + aoff[1][i]);
    }
    __builtin_amdgcn_s_setprio(1);
#pragma unroll
    for (int jj = 0; jj < 4; ++jj) {
      i32x4 b0 = *(const i32x4*)(lB + boff[0][jj]);
      i32x4 b1 = *(const i32x4*)(lB + boff[1][jj]);
#pragma unroll
      for (int i = 0; i < 4; ++i) {
        i32x4 zero = {0, 0, 0, 0};
        i32x4 ic = __builtin_amdgcn_mfma_i32_16x16x64_i8(a[i][0], b0, zero, 0, 0, 0);
        ic = __builtin_amdgcn_mfma_i32_16x16x64_i8(a[i][1], b1, ic, 0, 0, 0);
        float ps = sxq[i] * sn[jj];
        f32x2 p2 = {ps, ps};
        f32x2 c01 = {(float)ic[0], (float)ic[1]};
        f32x2 c23 = {(float)ic[2], (float)ic[3]};
        fc[i][jj][0] = __builtin_elementwise_fma(c01, p2, fc[i][jj][0]);
        fc[i][jj][1] = __builtin_elementwise_fma(c23, p2, fc[i][jj][1]);
      }
    }
    __builtin_amdgcn_s_setprio(0);
    __syncthreads();
  }

  float bj[4];
#pragma unroll
  for (int jj = 0; jj < 4; ++jj) bj[jj] = bias[n0 + wc + jj * 16 + l16];

#pragma unroll
  for (int i = 0; i < 4; ++i)
#pragma unroll
    for (int jj = 0; jj < 4; ++jj)
#pragma unroll
      for (int r = 0; r < 4; ++r) {
        int m = m0 + wr + i * 16 + quad * 4 + r;
        int n = n0 + wc + jj * 16 + l16;
        out[(size_t)m * 3072 + n] = fc[i][jj][r >> 1][r & 1] + bj[jj];
      }
}

extern "C" void kernel_launch(void* const* d_in, const int* in_sizes, int n_in,
                              void* d_out, int out_size, void* d_ws, size_t ws_size,
                              hipStream_t stream) {
  const float* x        = (const float*)d_in[0];
  const int*   gup_qw   = (const int*)d_in[1];
  const int*   gup_qz   = (const int*)d_in[2];
  const float* gup_sc   = (const float*)d_in[3];
  const int*   down_qw  = (const int*)d_in[4];
  const int*   down_qz  = (const int*)d_in[5];
  const float* down_sc  = (const float*)d_in[6];
  const float* down_b   = (const float*)d_in[7];
  float* out = (float*)d_out;

  char* ws = (char*)d_ws;
  signed char* Xq    = (signed char*)(ws);                 // 12,582,912
  signed char* Wgupq = (signed char*)(ws + 12582912);      // 50,331,648
  signed char* Wdnq  = (signed char*)(ws + 62914560);      // 25,165,824
  signed char* Actq  = (signed char*)(ws + 88080384);      // 33,554,432
  float* Xs4 = (float*)(ws + 121634816);                   // 24x1024
  float* GsT = (float*)(ws + 121733120);                   // 24x16384
  float* DsT = (float*)(ws + 123305984);                   // 64x3072
  float* As4 = (float*)(ws + 124092416);                   // 64x1024

  quant_x<<<dim3(24, 1024), 256, 0, stream>>>(x, Xq, Xs4);
  requant_k<3072><<<24576, 256, 0, stream>>>(gup_qw, gup_qz, Wgupq);
  requant_k<8192><<<12288, 256, 0, stream>>>(down_qw, down_qz, Wdnq);
  transpose_sc<<<1536, 256, 0, stream>>>(gup_sc, GsT, 16384, 24);
  transpose_sc<<<768, 256, 0, stream>>>(down_sc, DsT, 3072, 64);
  gemm_gateup_i8<<<2048, 256, 0, stream>>>(Xq, Wgupq, Xs4, GsT, Actq, As4);
  gemm_down_i8<<<768, 256, 0, stream>>>(Actq, Wdnq, As4, DsT, down_b, out);
}

// Round 4
// 743.364 us; speedup vs baseline: 1.2890x; 1.0866x over previous
//
#include <hip/hip_runtime.h>

// Phi3 quantized MLP on MI355X (gfx950) — R9: flat-scale int32-accum GEMM1.
// R8 post-mortem: R5/R8 plateau (303-308 us) is work-saturation: MfmaUtil 29 +
// VALUBusy 46 = 75% issue-busy. Per wave-K-step: 64 MFMAs (294 cy) vs ~224 rescale
// VALU insts (448 cy) + 24 ds_read_b128 — the per-group dequant rescale VALU alone
// exceeds the MFMA pipe. R9 removes it for GEMM1: weights requantized per-ROW flat
// int8 (w8 = round((q-z)*s_g/rs), rs = 15*smax_row/127), X quantized per-row-quad
// over FULL K (absmax over 3072, 1.24x coarser). All scales now constant along K ->
// K-loop is pure MFMA chaining into int32 accumulators (3072*127^2 < 2^31), one
// dequant at the epilogue. GEMM2 unchanged (act scale varies along its K).
// Mapping reverted to R5's (R8 cohort raised FETCH 152->257 MB for no gain).

typedef float f32x4 __attribute__((ext_vector_type(4)));
typedef float f32x2 __attribute__((ext_vector_type(2)));
typedef int   i32x4 __attribute__((ext_vector_type(4)));

__device__ __forceinline__ void gload16(const void* g, void* l) {
  __builtin_amdgcn_global_load_lds(
      (const __attribute__((address_space(1))) void*)g,
      (__attribute__((address_space(3))) void*)l, 16, 0, 0);
}

// ---------------- quantize x: f32 -> int8, ONE scale per row-quad (4 rows x full K) ----------------
// grid 1024: block = row-quad. Xs: [1024]
__global__ __launch_bounds__(256) void quant_x_flat(const float* __restrict__ x,
                                                    signed char* __restrict__ Xq,
                                                    float* __restrict__ Xs) {
  int rq   = blockIdx.x;
  int w    = threadIdx.x >> 6;
  int lane = threadIdx.x & 63;
  size_t rowbase = ((size_t)rq * 4 + w) * 3072;
  __shared__ float wmax[4];
  float4 v[12];
  float m = 0.f;
#pragma unroll
  for (int it = 0; it < 12; ++it) {
    v[it] = *(const float4*)(x + rowbase + (lane + it * 64) * 4);
    m = fmaxf(m, fmaxf(fmaxf(fabsf(v[it].x), fabsf(v[it].y)),
                       fmaxf(fabsf(v[it].z), fabsf(v[it].w))));
  }
#pragma unroll
  for (int s = 1; s < 64; s <<= 1) m = fmaxf(m, __shfl_xor(m, s));
  if (lane == 0) wmax[w] = m;
  __syncthreads();
  float m4 = fmaxf(fmaxf(wmax[0], wmax[1]), fmaxf(wmax[2], wmax[3]));
  float inv = m4 > 0.f ? 127.f / m4 : 0.f;
#pragma unroll
  for (int it = 0; it < 12; ++it) {
    int a = (int)rintf(v[it].x * inv);
    int b = (int)rintf(v[it].y * inv);
    int c = (int)rintf(v[it].z * inv);
    int d = (int)rintf(v[it].w * inv);
    int pk = (a & 0xff) | ((b & 0xff) << 8) | ((c & 0xff) << 16) | ((d & 0xff) << 24);
    *(int*)(Xq + rowbase + (lane + it * 64) * 4) = pk;
  }
  if (threadIdx.x == 0) Xs[rq] = m4 * (1.f / 127.f);
}

// ---------------- requant gate/up weights: per-ROW flat int8 + row scale ----------------
// w8 = round((q-z)*s_g / rs), rs = 15*max_g(s_g)/127  (|w8| <= 127 guaranteed)
__global__ __launch_bounds__(256) void requant_gup_flat(const int* __restrict__ qw,
                                                        const int* __restrict__ qz,
                                                        const float* __restrict__ sc,
                                                        signed char* __restrict__ W,
                                                        float* __restrict__ Ws) {
  int w    = threadIdx.x >> 6;
  int lane = threadIdx.x & 63;
  int r    = blockIdx.x * 4 + w;
  float smax = (lane < 24) ? sc[r * 24 + lane] : 0.f;
#pragma unroll
  for (int s = 1; s < 64; s <<= 1) smax = fmaxf(smax, __shfl_xor(smax, s));
  float rs    = smax * (15.f / 127.f);
  float invrs = 127.f / (15.f * smax);
#pragma unroll
  for (int it = 0; it < 12; ++it) {
    int cidx = lane + it * 64;           // int4 index; covers elements 4*cidx..4*cidx+3
    int g    = cidx >> 5;                // (4*cidx)>>7
    int z    = qz[r * 24 + g];
    float f  = sc[r * 24 + g] * invrs;
    int4 q   = *(const int4*)(qw + (size_t)r * 3072 + cidx * 4);
    int a = (int)rintf((float)(q.x - z) * f);
    int b = (int)rintf((float)(q.y - z) * f);
    int c = (int)rintf((float)(q.z - z) * f);
    int d = (int)rintf((float)(q.w - z) * f);
    int pk = (a & 0xff) | ((b & 0xff) << 8) | ((c & 0xff) << 16) | ((d & 0xff) << 24);
    *(int*)(W + (size_t)r * 3072 + cidx * 4) = pk;
  }
  if (lane == 0) Ws[r] = rs;
}

// ---------------- requant down weights: int32 q,z -> int8 (q - z), exact ----------------
template <int K>
__global__ __launch_bounds__(256) void requant_k(const int* __restrict__ qw,
                                                 const int* __restrict__ qz,
                                                 signed char* __restrict__ W) {
  constexpr int KG = K / 128;
  constexpr int perrow = K / 8;
  int idx = blockIdx.x * 256 + threadIdx.x;
  int row = idx / perrow;
  int c8  = idx - row * perrow;
  int k   = c8 << 3;
  int z   = qz[row * KG + (k >> 7)];
  const int4* q4 = (const int4*)(qw + (size_t)row * K + k);
  int4 qa = q4[0];
  int4 qb = q4[1];
  int b0 = ((qa.x - z) & 0xff) | (((qa.y - z) & 0xff) << 8) |
           (((qa.z - z) & 0xff) << 16) | (((qa.w - z) & 0xff) << 24);
  int b1 = ((qb.x - z) & 0xff) | (((qb.y - z) & 0xff) << 8) |
           (((qb.z - z) & 0xff) << 16) | (((qb.w - z) & 0xff) << 24);
  int2 o; o.x = b0; o.y = b1;
  *(int2*)(W + (size_t)row * K + k) = o;
}

// ---------------- scale transpose: [R][G] -> [G][R] ----------------
__global__ __launch_bounds__(256) void transpose_sc(const float* __restrict__ in,
                                                    float* __restrict__ out,
                                                    int R, int G) {
  int idx = blockIdx.x * 256 + threadIdx.x;
  int r = idx / G;
  int g = idx - r * G;
  out[(size_t)g * R + r] = in[idx];
}

// LDS tile: 128 rows x 128 bytes, XOR-swizzled (phys chunk p holds logical p^(row&7)).

// ---------------- GEMM1: act = silu(x@Wg^T)*(x@Wu^T), flat int8, pure int32 K-loop ----------------
__global__ __launch_bounds__(256, 2) void gemm_gateup_i8(
    const signed char* __restrict__ Xq, const signed char* __restrict__ Wq,
    const float* __restrict__ Xs,    // [1024] per-row-quad x scale
    const float* __restrict__ WsG,   // [16384] per-row weight scale (gate rows then up rows)
    signed char* __restrict__ act,   // [4096][8192]
    float* __restrict__ As4) {       // [64][1024]
  const int K = 3072;
  const int bid = blockIdx.x;
  const int xcd = bid & 7;
  const int jb  = bid >> 3;
  const int n0  = ((xcd << 3) + (jb & 7)) * 128;
  const int m0  = (jb >> 3) * 128;
  __shared__ signed char lA[16384];
  __shared__ signed char lG[16384];
  __shared__ signed char lU[16384];
  __shared__ float rmax[2][128];
  __shared__ float rmax4[32];

  const int tid  = threadIdx.x;
  const int l    = tid & 63;
  const int quad = l >> 4;
  const int l16  = l & 15;
  const int wcI  = (tid >> 6) & 1;
  const int wr   = ((tid >> 6) >> 1) * 64;
  const int wc   = wcI * 64;

  i32x4 accg[4][4] = {};
  i32x4 accu[4][4] = {};

  int off[4];
#pragma unroll
  for (int jj = 0; jj < 4; ++jj) {
    int c   = tid + 256 * jj;
    int row = c >> 3;
    int log = (c & 7) ^ (row & 7);
    off[jj] = row * K + log * 16;
  }
  const signed char* baseA = Xq + (size_t)m0 * K;
  const signed char* baseG = Wq + (size_t)n0 * K;
  const signed char* baseU = Wq + (size_t)(8192 + n0) * K;

  int aoff[2][4], boff[2][4];
#pragma unroll
  for (int h = 0; h < 2; ++h) {
    int slot = h * 4 + quad;
#pragma unroll
    for (int i = 0; i < 4; ++i) {
      int ra = wr + i * 16 + l16;
      aoff[h][i] = ra * 128 + ((slot ^ (ra & 7)) * 16);
      int rb = wc + i * 16 + l16;
      boff[h][i] = rb * 128 + ((slot ^ (rb & 7)) * 16);
    }
  }
  const int qbase = (m0 >> 2) + (wr >> 2) + quad;   // row-quad index base (i adds i*4)

  for (int g = 0; g < 24; ++g) {
    const int kk = g << 7;
#pragma unroll
    for (int jj = 0; jj < 4; ++jj) {
      gload16(baseA + off[jj] + kk, lA + (tid + 256 * jj) * 16);
      gload16(baseG + off[jj] + kk, lG + (tid + 256 * jj) * 16);
      gload16(baseU + off[jj] + kk, lU + (tid + 256 * jj) * 16);
    }
    __syncthreads();

    i32x4 a[4][2];
#pragma unroll
    for (int i = 0; i < 4; ++i) {
      a[i][0] = *(const i32x4*)(lA + aoff[0][i]);
      a[i][1] = *(const i32x4*)(lA + aoff[1][i]);
    }
    __builtin_amdgcn_s_setprio(1);
#pragma unroll
    for (int jj = 0; jj < 4; ++jj) {
      i32x4 bg0 = *(const i32x4*)(lG + boff[0][jj]);
      i32x4 bg1 = *(const i32x4*)(lG + boff[1][jj]);
      i32x4 bu0 = *(const i32x4*)(lU + boff[0][jj]);
      i32x4 bu1 = *(const i32x4*)(lU + boff[1][jj]);
#pragma unroll
      for (int i = 0; i < 4; ++i) {
        accg[i][jj] = __builtin_amdgcn_mfma_i32_16x16x64_i8(a[i][0], bg0, accg[i][jj], 0, 0, 0);
        accg[i][jj] = __builtin_amdgcn_mfma_i32_16x16x64_i8(a[i][1], bg1, accg[i][jj], 0, 0, 0);
        accu[i][jj] = __builtin_amdgcn_mfma_i32_16x16x64_i8(a[i][0], bu0, accu[i][jj], 0, 0, 0);
        accu[i][jj] = __builtin_amdgcn_mfma_i32_16x16x64_i8(a[i][1], bu1, accu[i][jj], 0, 0, 0);
      }
    }
    __builtin_amdgcn_s_setprio(0);
    __syncthreads();
  }

  // ---- epilogue: dequant (flat scales) -> silu(g)*u -> quad-shared absmax -> int8 ----
  float sxf[4], wsg[4], wsu[4];
#pragma unroll
  for (int i = 0; i < 4; ++i) sxf[i] = Xs[qbase + i * 4];
#pragma unroll
  for (int jj = 0; jj < 4; ++jj) {
    wsg[jj] = WsG[n0 + wc + jj * 16 + l16];
    wsu[jj] = WsG[8192 + n0 + wc + jj * 16 + l16];
  }

  float av[4][4][4];   // [i][jj][r]
#pragma unroll
  for (int i = 0; i < 4; ++i)
#pragma unroll
    for (int jj = 0; jj < 4; ++jj) {
      float pg = sxf[i] * wsg[jj];
      float pu = sxf[i] * wsu[jj];
#pragma unroll
      for (int r = 0; r < 4; ++r) {
        float gv = (float)accg[i][jj][r] * pg;
        float uv = (float)accu[i][jj][r] * pu;
        av[i][jj][r] = (gv / (1.f + __expf(-gv))) * uv;
      }
    }

#pragma unroll
  for (int i = 0; i < 4; ++i)
#pragma unroll
    for (int r = 0; r < 4; ++r) {
      float m = 0.f;
#pragma unroll
      for (int jj = 0; jj < 4; ++jj) m = fmaxf(m, fabsf(av[i][jj][r]));
      m = fmaxf(m, __shfl_xor(m, 1));
      m = fmaxf(m, __shfl_xor(m, 2));
      m = fmaxf(m, __shfl_xor(m, 4));
      m = fmaxf(m, __shfl_xor(m, 8));
      if (l16 == 0) rmax[wcI][wr + i * 16 + quad * 4 + r] = m;
    }
  __syncthreads();
  if (tid < 32) {
    float m = 0.f;
#pragma unroll
    for (int k = 0; k < 4; ++k)
      m = fmaxf(m, fmaxf(rmax[0][tid * 4 + k], rmax[1][tid * 4 + k]));
    rmax4[tid] = m;
    As4[(n0 >> 7) * 1024 + (m0 >> 2) + tid] = m * (1.f / 127.f);
  }
  __syncthreads();

#pragma unroll
  for (int i = 0; i < 4; ++i) {
    float mx = rmax4[(wr >> 2) + i * 4 + quad];
    float inv = mx > 0.f ? 127.f / mx : 0.f;
#pragma unroll
    for (int r = 0; r < 4; ++r) {
      int mrow = wr + i * 16 + quad * 4 + r;
#pragma unroll
      for (int jj = 0; jj < 4; ++jj) {
        int q = (int)rintf(av[i][jj][r] * inv);
        lA[mrow * 128 + wc + jj * 16 + l16] = (signed char)q;
      }
    }
  }
  __syncthreads();

#pragma unroll
  for (int t = 0; t < 4; ++t) {
    int c = tid + 256 * t;
    int row = c >> 3;
    int col = (c & 7) * 16;
    *(int4*)(act + (size_t)(m0 + row) * 8192 + n0 + col) = *(const int4*)(lA + row * 128 + col);
  }
}

// ---------------- GEMM2: out = dequant(act)@Wd^T + bias (unchanged, per-group rescale) ----------------
__global__ __launch_bounds__(256, 2) void gemm_down_i8(
    const signed char* __restrict__ Aq, const signed char* __restrict__ Wq,
    const float* __restrict__ As4,   // [64][1024]
    const float* __restrict__ DsT,   // [64][3072]
    const float* __restrict__ bias,
    float* __restrict__ out) {
  const int K = 8192;
  const int bid = blockIdx.x;
  const int xcd = bid & 7;
  const int jb  = bid >> 3;
  const int jn  = jb % 12;
  const int jm  = jb / 12;
  const int n0  = (12 * (xcd & 1) + jn) * 128;
  const int m0  = (8 * (xcd >> 1) + jm) * 128;
  __shared__ signed char lA[16384];
  __shared__ signed char lB[16384];

  const int tid  = threadIdx.x;
  const int l    = tid & 63;
  const int quad = l >> 4;
  const int l16  = l & 15;
  const int wr   = ((tid >> 6) >> 1) * 64;
  const int wc   = ((tid >> 6) & 1) * 64;

  f32x2 fc[4][4][2] = {};

  int off[4];
#pragma unroll
  for (int jj = 0; jj < 4; ++jj) {
    int c   = tid + 256 * jj;
    int row = c >> 3;
    int log = (c & 7) ^ (row & 7);
    off[jj] = row * K + log * 16;
  }
  const signed char* baseA = Aq + (size_t)m0 * K;
  const signed char* baseB = Wq + (size_t)n0 * K;

  int aoff[2][4], boff[2][4];
#pragma unroll
  for (int h = 0; h < 2; ++h) {
    int slot = h * 4 + quad;
#pragma unroll
    for (int i = 0; i < 4; ++i) {
      int ra = wr + i * 16 + l16;
      aoff[h][i] = ra * 128 + ((slot ^ (ra & 7)) * 16);
      int rb = wc + i * 16 + l16;
      boff[h][i] = rb * 128 + ((slot ^ (rb & 7)) * 16);
    }
  }
  const int qbase = (m0 >> 2) + (wr >> 2) + quad;

  for (int g = 0; g < 64; ++g) {
    const int kk = g << 7;
#pragma unroll
    for (int jj = 0; jj < 4; ++jj) {
      gload16(baseA + off[jj] + kk, lA + (tid + 256 * jj) * 16);
      gload16(baseB + off[jj] + kk, lB + (tid + 256 * jj) * 16);
    }
    float sxq[4], sn[4];
#pragma unroll
    for (int i = 0; i < 4; ++i) sxq[i] = As4[g * 1024 + qbase + i * 4];
#pragma unroll
    for (int jj = 0; jj < 4; ++jj)
      sn[jj] = DsT[g * 3072 + n0 + wc + jj * 16 + l16];
    __syncthreads();

    i32x4 a[4][2];
#pragma unroll
    for (int i = 0; i < 4; ++i) {
      a[i][0] = *(const i32x4*)(lA + aoff[0][i]);
      a[i][1] = *(const i32x4*)(lA + aoff[1][i]);
    }
    __builtin_amdgcn_s_setprio(1);
#pragma unroll
    for (int jj = 0; jj < 4; ++jj) {
      i32x4 b0 = *(const i32x4*)(lB + boff[0][jj]);
      i32x4 b1 = *(const i32x4*)(lB + boff[1][jj]);
#pragma unroll
      for (int i = 0; i < 4; ++i) {
        i32x4 zero = {0, 0, 0, 0};
        i32x4 ic = __builtin_amdgcn_mfma_i32_16x16x64_i8(a[i][0], b0, zero, 0, 0, 0);
        ic = __builtin_amdgcn_mfma_i32_16x16x64_i8(a[i][1], b1, ic, 0, 0, 0);
        float ps = sxq[i] * sn[jj];
        f32x2 p2 = {ps, ps};
        f32x2 c01 = {(float)ic[0], (float)ic[1]};
        f32x2 c23 = {(float)ic[2], (float)ic[3]};
        fc[i][jj][0] = __builtin_elementwise_fma(c01, p2, fc[i][jj][0]);
        fc[i][jj][1] = __builtin_elementwise_fma(c23, p2, fc[i][jj][1]);
      }
    }
    __builtin_amdgcn_s_setprio(0);
    __syncthreads();
  }

  float bj[4];
#pragma unroll
  for (int jj = 0; jj < 4; ++jj) bj[jj] = bias[n0 + wc + jj * 16 + l16];

#pragma unroll
  for (int i = 0; i < 4; ++i)
#pragma unroll
    for (int jj = 0; jj < 4; ++jj)
#pragma unroll
      for (int r = 0; r < 4; ++r) {
        int m = m0 + wr + i * 16 + quad * 4 + r;
        int n = n0 + wc + jj * 16 + l16;
        out[(size_t)m * 3072 + n] = fc[i][jj][r >> 1][r & 1] + bj[jj];
      }
}

extern "C" void kernel_launch(void* const* d_in, const int* in_sizes, int n_in,
                              void* d_out, int out_size, void* d_ws, size_t ws_size,
                              hipStream_t stream) {
  const float* x        = (const float*)d_in[0];
  const int*   gup_qw   = (const int*)d_in[1];
  const int*   gup_qz   = (const int*)d_in[2];
  const float* gup_sc   = (const float*)d_in[3];
  const int*   down_qw  = (const int*)d_in[4];
  const int*   down_qz  = (const int*)d_in[5];
  const float* down_sc  = (const float*)d_in[6];
  const float* down_b   = (const float*)d_in[7];
  float* out = (float*)d_out;

  char* ws = (char*)d_ws;
  signed char* Xq    = (signed char*)(ws);                 // 12,582,912
  signed char* Wgupq = (signed char*)(ws + 12582912);      // 50,331,648
  signed char* Wdnq  = (signed char*)(ws + 62914560);      // 25,165,824
  signed char* Actq  = (signed char*)(ws + 88080384);      // 33,554,432
  float* Xs  = (float*)(ws + 121634816);                   // 1024 f32
  float* WsG = (float*)(ws + 121638912);                   // 16384 f32
  float* DsT = (float*)(ws + 121704448);                   // 64x3072 f32
  float* As4 = (float*)(ws + 122490880);                   // 64x1024 f32

  quant_x_flat<<<1024, 256, 0, stream>>>(x, Xq, Xs);
  requant_gup_flat<<<4096, 256, 0, stream>>>(gup_qw, gup_qz, gup_sc, Wgupq, WsG);
  requant_k<8192><<<12288, 256, 0, stream>>>(down_qw, down_qz, Wdnq);
  transpose_sc<<<768, 256, 0, stream>>>(down_sc, DsT, 3072, 64);
  gemm_gateup_i8<<<2048, 256, 0, stream>>>(Xq, Wgupq, Xs, WsG, Actq, As4);
  gemm_down_i8<<<768, 256, 0, stream>>>(Actq, Wdnq, As4, DsT, down_b, out);
}